// Round 18
// baseline (221.453 us; speedup 1.0000x reference)
//
#include <hip/hip_runtime.h>
#include <math.h>

#define N_NODES 50000
#define M_NBR 16
#define D 128
#define E 64

typedef __attribute__((ext_vector_type(8))) __bf16 bf16x8;
typedef __attribute__((ext_vector_type(4))) float f32x4;

// async global->LDS (HW: per-lane global src; wave-uniform LDS base + lane*16)
__device__ __forceinline__ void gload16(const void* g, void* l) {
  __builtin_amdgcn_global_load_lds(
      (const __attribute__((address_space(1))) void*)g,
      (__attribute__((address_space(3))) void*)l, 16, 0, 0);
}

#define FENCE() asm volatile("" ::: "memory")

// W1c LDS swizzle (involution)
__device__ __forceinline__ int swz(int o) { return o ^ (((o >> 7) & 7) << 4); }

// ---------------------------------------------------------------------------
// ABLATION A: nbr stream + W1c-LDS MFMA only (R17 phase-2 shape, no gather/silu)
// ---------------------------------------------------------------------------
__global__ __launch_bounds__(256, 3) void kA_stream(const float* __restrict__ nbr,
                                                    const __bf16* __restrict__ w1c_f,
                                                    float* __restrict__ scratch) {
  __shared__ __bf16 wlds[8192];
  const int lane = threadIdx.x & 63;
  const int wid  = threadIdx.x >> 6;
  const int r = lane & 15, c = lane >> 4;
  {
    const int s0 = wid * 1024 + lane * 16;
    #pragma unroll
    for (int q = 0; q < 4; ++q) {
      const int s = s0 + q * 4096;
      gload16((const char*)w1c_f + swz(s), (char*)wlds + s);
    }
  }
  __syncthreads();

  const int node0 = (blockIdx.x * 4 + wid) * 4;
  float ssum = 0.f;

  f32x4 pa0, pa1, pa2, pa3, qa0, qa1, qa2, qa3;
  {
    const float* ar = nbr + (size_t)(node0 + 0) * (M_NBR * E) + r * E + c * 8;
    pa0 = *(const f32x4*)(ar); pa1 = *(const f32x4*)(ar + 4);
    pa2 = *(const f32x4*)(ar + 32); pa3 = *(const f32x4*)(ar + 36);
  }
  {
    const float* ar = nbr + (size_t)(node0 + 1) * (M_NBR * E) + r * E + c * 8;
    qa0 = *(const f32x4*)(ar); qa1 = *(const f32x4*)(ar + 4);
    qa2 = *(const f32x4*)(ar + 32); qa3 = *(const f32x4*)(ar + 36);
  }
  FENCE();
  #pragma unroll
  for (int i = 0; i < 4; ++i) {
    f32x4 a0 = pa0, a1 = pa1, a2 = pa2, a3 = pa3;
    // rotate pipeline
    pa0 = qa0; pa1 = qa1; pa2 = qa2; pa3 = qa3;
    if (i < 2) {
      const float* ar = nbr + (size_t)(node0 + i + 2) * (M_NBR * E) + r * E + c * 8;
      qa0 = *(const f32x4*)(ar); qa1 = *(const f32x4*)(ar + 4);
      qa2 = *(const f32x4*)(ar + 32); qa3 = *(const f32x4*)(ar + 36);
    }
    FENCE();
    bf16x8 af0, af1;
    #pragma unroll
    for (int e = 0; e < 4; ++e) {
      af0[e] = (__bf16)a0[e]; af0[4 + e] = (__bf16)a1[e];
      af1[e] = (__bf16)a2[e]; af1[4 + e] = (__bf16)a3[e];
    }
    f32x4 acc[8];
    #pragma unroll
    for (int dt = 0; dt < 8; ++dt) acc[dt] = (f32x4){0, 0, 0, 0};
    #pragma unroll
    for (int dt = 0; dt < 8; ++dt) {
      const int o0 = ((dt * 2 + 0) * 64 + c * 16 + r) * 16;
      const int o1 = ((dt * 2 + 1) * 64 + c * 16 + r) * 16;
      const bf16x8 b0 = *(const bf16x8*)((const char*)wlds + swz(o0));
      const bf16x8 b1 = *(const bf16x8*)((const char*)wlds + swz(o1));
      acc[dt] = __builtin_amdgcn_mfma_f32_16x16x32_bf16(af0, b0, acc[dt], 0, 0, 0);
      acc[dt] = __builtin_amdgcn_mfma_f32_16x16x32_bf16(af1, b1, acc[dt], 0, 0, 0);
    }
    #pragma unroll
    for (int dt = 0; dt < 8; ++dt)
      ssum += acc[dt][0] + acc[dt][1] + acc[dt][2] + acc[dt][3];
  }
  scratch[(size_t)blockIdx.x * 256 + threadIdx.x] = ssum;
}

// ---------------------------------------------------------------------------
// ABLATION B: idx -> t2 gathers + t1 loads + sum only (no nbr, no MFMA)
// ---------------------------------------------------------------------------
__global__ __launch_bounds__(256, 3) void kB_gather(const int* __restrict__ idx,
                                                    const __bf16* __restrict__ t1bp,
                                                    const __bf16* __restrict__ t2bp,
                                                    float* __restrict__ scratch) {
  const int lane = threadIdx.x & 63;
  const int wid  = threadIdx.x >> 6;
  const int r = lane & 15, c = lane >> 4;
  const int node0 = (blockIdx.x * 4 + wid) * 4;

  const int4 g0 = *(const int4*)(idx + (node0 + 0) * M_NBR + c * 4);
  const int4 g1 = *(const int4*)(idx + (node0 + 1) * M_NBR + c * 4);
  const int4 g2 = *(const int4*)(idx + (node0 + 2) * M_NBR + c * 4);
  const int4 g3 = *(const int4*)(idx + (node0 + 3) * M_NBR + c * 4);
  float ssum = 0.f;
  #pragma unroll
  for (int i = 0; i < 4; ++i) {
    const int4 g = (i == 0) ? g0 : (i == 1) ? g1 : (i == 2) ? g2 : g3;
    const int n = node0 + i;
    const bf16x8 t1v = *(const bf16x8*)(t1bp + (size_t)n * 128 + r * 8);
    const bf16x8 tg0 = *(const bf16x8*)(t2bp + (size_t)g.x * 128 + r * 8);
    const bf16x8 tg1 = *(const bf16x8*)(t2bp + (size_t)g.y * 128 + r * 8);
    const bf16x8 tg2 = *(const bf16x8*)(t2bp + (size_t)g.z * 128 + r * 8);
    const bf16x8 tg3 = *(const bf16x8*)(t2bp + (size_t)g.w * 128 + r * 8);
    FENCE();
    #pragma unroll
    for (int dt = 0; dt < 8; ++dt)
      ssum += (float)t1v[dt] + (float)tg0[dt] + (float)tg1[dt]
            + (float)tg2[dt] + (float)tg3[dt];
  }
  scratch[(size_t)blockIdx.x * 256 + threadIdx.x] = ssum;
}

// ---------------------------------------------------------------------------
// ABLATION C: register-only silu epilogue (128 independent exp+rcp per lane)
// ---------------------------------------------------------------------------
__global__ __launch_bounds__(256, 3) void kC_silu(float* __restrict__ scratch) {
  const float base = threadIdx.x * 0.001f + blockIdx.x * 0.00001f;
  float ssum = 0.f;
  #pragma unroll
  for (int i = 0; i < 4; ++i) {
    #pragma unroll
    for (int dt = 0; dt < 8; ++dt) {
      #pragma unroll
      for (int j = 0; j < 4; ++j) {
        const float h = base + i * 0.3f + dt * 0.1f + j * 0.01f;
        ssum += __fdividef(h, 1.0f + __expf(-h));
      }
    }
  }
  scratch[(size_t)blockIdx.x * 256 + threadIdx.x] = ssum;
}

// ===========================================================================
// REAL PIPELINE — byte-identical to R17 (best-known, 114.7 us)
// ===========================================================================
__global__ __launch_bounds__(256) void k_prep(const float* __restrict__ W1,
                                              const float* __restrict__ W2,
                                              __bf16* __restrict__ w1a_f,
                                              __bf16* __restrict__ w1b_f,
                                              __bf16* __restrict__ w1c_f,
                                              __bf16* __restrict__ w2_f) {
  const int t = blockIdx.x * 256 + threadIdx.x;
  if (t < 16384) {
    const int j = t & 7, r = (t >> 3) & 15, c = (t >> 7) & 3, q = t >> 9;
    const int kt = q & 3, dt = q >> 2;
    w1a_f[t] = (__bf16)W1[(kt * 32 + c * 8 + j) * 128 + dt * 16 + r];
  } else if (t < 32768) {
    const int u = t - 16384;
    const int j = u & 7, r = (u >> 3) & 15, c = (u >> 7) & 3, q = u >> 9;
    const int kt = q & 3, dt = q >> 2;
    w1b_f[u] = (__bf16)W1[(128 + kt * 32 + c * 8 + j) * 128 + dt * 16 + r];
  } else if (t < 40960) {
    const int u = t - 32768;
    const int j = u & 7, r = (u >> 3) & 15, c = (u >> 7) & 3, q = u >> 9;
    const int kt = q & 1, dt = q >> 1;
    w1c_f[u] = (__bf16)W1[(256 + kt * 32 + c * 8 + j) * 128 + dt * 16 + r];
  } else if (t < 57344) {
    const int u = t - 40960;
    const int j = u & 7, r = (u >> 3) & 15, c = (u >> 7) & 3, q = u >> 9;
    const int kt = q & 3, dt = q >> 2;
    w2_f[u] = (__bf16)W2[(kt * 32 + c * 8 + j) * 128 + dt * 16 + r];
  }
}

__global__ __launch_bounds__(256) void k_t12f(const float* __restrict__ x,
                                              const float* __restrict__ sc,
                                              const float* __restrict__ bi,
                                              const __bf16* __restrict__ w1a_f,
                                              const __bf16* __restrict__ w1b_f,
                                              const float* __restrict__ b1,
                                              __bf16* __restrict__ t1bp,
                                              __bf16* __restrict__ t2bp) {
  const int wave = blockIdx.x * 4 + (threadIdx.x >> 6);
  if (wave >= N_NODES / 16) return;
  const int lane = threadIdx.x & 63;
  const int r = lane & 15, c = lane >> 4;
  const int node0 = wave * 16;

  const float* row = x + (size_t)(node0 + r) * 128 + c * 8;
  f32x4 va[8];
  #pragma unroll
  for (int kt = 0; kt < 4; ++kt) {
    va[2 * kt]     = *(const f32x4*)(row + kt * 32);
    va[2 * kt + 1] = *(const f32x4*)(row + kt * 32 + 4);
  }
  float s = 0.f;
  #pragma unroll
  for (int q = 0; q < 8; ++q) s += va[q][0] + va[q][1] + va[q][2] + va[q][3];
  s += __shfl_xor(s, 16, 64);
  s += __shfl_xor(s, 32, 64);
  const float mu = s * (1.0f / 128.0f);
  float qs = 0.f;
  #pragma unroll
  for (int q = 0; q < 8; ++q) {
    #pragma unroll
    for (int e = 0; e < 4; ++e) { const float dxx = va[q][e] - mu; qs += dxx * dxx; }
  }
  qs += __shfl_xor(qs, 16, 64);
  qs += __shfl_xor(qs, 32, 64);
  const float rs = rsqrtf(qs * (1.0f / 128.0f) + 1e-6f);

  bf16x8 af[4];
  #pragma unroll
  for (int kt = 0; kt < 4; ++kt) {
    const f32x4 s_lo = *(const f32x4*)(sc + kt * 32 + c * 8);
    const f32x4 s_hi = *(const f32x4*)(sc + kt * 32 + c * 8 + 4);
    const f32x4 b_lo = *(const f32x4*)(bi + kt * 32 + c * 8);
    const f32x4 b_hi = *(const f32x4*)(bi + kt * 32 + c * 8 + 4);
    #pragma unroll
    for (int e = 0; e < 4; ++e) {
      af[kt][e]     = (__bf16)(((va[2 * kt][e]     - mu) * rs) * s_lo[e] + b_lo[e]);
      af[kt][4 + e] = (__bf16)(((va[2 * kt + 1][e] - mu) * rs) * s_hi[e] + b_hi[e]);
    }
  }

  const bf16x8* wa = (const bf16x8*)w1a_f;
  const bf16x8* wb = (const bf16x8*)w1b_f;
  f32x4 acc1[8], acc2[8];
  #pragma unroll
  for (int dt = 0; dt < 8; ++dt) { acc1[dt] = (f32x4){0,0,0,0}; acc2[dt] = (f32x4){0,0,0,0}; }
  #pragma unroll
  for (int dt = 0; dt < 8; ++dt) {
    #pragma unroll
    for (int kt = 0; kt < 4; ++kt) {
      const bf16x8 bfa = wa[(dt * 4 + kt) * 64 + c * 16 + r];
      acc1[dt] = __builtin_amdgcn_mfma_f32_16x16x32_bf16(af[kt], bfa, acc1[dt], 0, 0, 0);
      const bf16x8 bfb = wb[(dt * 4 + kt) * 64 + c * 16 + r];
      acc2[dt] = __builtin_amdgcn_mfma_f32_16x16x32_bf16(af[kt], bfb, acc2[dt], 0, 0, 0);
    }
  }

  float b1v[8];
  #pragma unroll
  for (int dt = 0; dt < 8; ++dt) b1v[dt] = b1[dt * 16 + r];
  #pragma unroll
  for (int j = 0; j < 4; ++j) {
    const int node = node0 + c * 4 + j;
    bf16x8 t1v, t2v;
    #pragma unroll
    for (int dt = 0; dt < 8; ++dt) {
      t1v[dt] = (__bf16)(acc1[dt][j] + b1v[dt]);
      t2v[dt] = (__bf16)acc2[dt][j];
    }
    *(bf16x8*)(t1bp + (size_t)node * 128 + r * 8) = t1v;
    *(bf16x8*)(t2bp + (size_t)node * 128 + r * 8) = t2v;
  }
}

#define HPITCH 136

struct NL {
  f32x4 a0, a1, a2, a3;
  bf16x8 t1v;
  bf16x8 tg0, tg1, tg2, tg3;
};

__device__ __forceinline__ NL load_node(const float* __restrict__ nbr,
                                        const __bf16* __restrict__ t1bp,
                                        const __bf16* __restrict__ t2bp,
                                        int n, int4 g, int r, int c) {
  NL v;
  const float* arow = nbr + (size_t)n * (M_NBR * E) + r * E + c * 8;
  v.a0 = *(const f32x4*)(arow);
  v.a1 = *(const f32x4*)(arow + 4);
  v.a2 = *(const f32x4*)(arow + 32);
  v.a3 = *(const f32x4*)(arow + 36);
  v.t1v = *(const bf16x8*)(t1bp + (size_t)n * 128 + r * 8);
  v.tg0 = *(const bf16x8*)(t2bp + (size_t)g.x * 128 + r * 8);
  v.tg1 = *(const bf16x8*)(t2bp + (size_t)g.y * 128 + r * 8);
  v.tg2 = *(const bf16x8*)(t2bp + (size_t)g.z * 128 + r * 8);
  v.tg3 = *(const bf16x8*)(t2bp + (size_t)g.w * 128 + r * 8);
  return v;
}

__device__ __forceinline__ void compute_node(const NL& v, const __bf16* wlds,
                                             __bf16* hlds, int row,
                                             int lane, int r, int c) {
  bf16x8 af0, af1;
  #pragma unroll
  for (int e = 0; e < 4; ++e) {
    af0[e] = (__bf16)v.a0[e]; af0[4 + e] = (__bf16)v.a1[e];
    af1[e] = (__bf16)v.a2[e]; af1[4 + e] = (__bf16)v.a3[e];
  }
  f32x4 acc[8];
  #pragma unroll
  for (int dt = 0; dt < 8; ++dt) acc[dt] = (f32x4){0, 0, 0, 0};
  #pragma unroll
  for (int dt = 0; dt < 8; ++dt) {
    const int o0 = ((dt * 2 + 0) * 64 + c * 16 + r) * 16;
    const int o1 = ((dt * 2 + 1) * 64 + c * 16 + r) * 16;
    const bf16x8 b0 = *(const bf16x8*)((const char*)wlds + swz(o0));
    const bf16x8 b1 = *(const bf16x8*)((const char*)wlds + swz(o1));
    acc[dt] = __builtin_amdgcn_mfma_f32_16x16x32_bf16(af0, b0, acc[dt], 0, 0, 0);
    acc[dt] = __builtin_amdgcn_mfma_f32_16x16x32_bf16(af1, b1, acc[dt], 0, 0, 0);
  }
  #pragma unroll
  for (int dt = 0; dt < 8; ++dt) {
    const float tb = (float)v.t1v[dt];
    float s = 0.f;
    { const float h = acc[dt][0] + tb + (float)v.tg0[dt]; s += __fdividef(h, 1.0f + __expf(-h)); }
    { const float h = acc[dt][1] + tb + (float)v.tg1[dt]; s += __fdividef(h, 1.0f + __expf(-h)); }
    { const float h = acc[dt][2] + tb + (float)v.tg2[dt]; s += __fdividef(h, 1.0f + __expf(-h)); }
    { const float h = acc[dt][3] + tb + (float)v.tg3[dt]; s += __fdividef(h, 1.0f + __expf(-h)); }
    s += __shfl_xor(s, 16, 64);
    s += __shfl_xor(s, 32, 64);
    if (lane < 16) hlds[row * HPITCH + dt * 16 + lane] = (__bf16)s;
  }
}

__global__ __launch_bounds__(256, 3) void k_edge2(const float* __restrict__ nbr,
                                                  const int* __restrict__ idx,
                                                  const __bf16* __restrict__ t1bp,
                                                  const __bf16* __restrict__ t2bp,
                                                  const __bf16* __restrict__ w1c_f,
                                                  const __bf16* __restrict__ w2_f,
                                                  const float* __restrict__ b2,
                                                  const float* __restrict__ x,
                                                  float* __restrict__ out) {
  __shared__ __bf16 wlds[8192];
  __shared__ __bf16 hlds[16 * HPITCH];
  const int lane = threadIdx.x & 63;
  const int wid  = threadIdx.x >> 6;
  const int r = lane & 15, c = lane >> 4;
  const int nb0 = blockIdx.x * 16;
  const int row0 = wid * 4;

  {
    const int s0 = wid * 1024 + lane * 16;
    #pragma unroll
    for (int q = 0; q < 4; ++q) {
      const int s = s0 + q * 4096;
      gload16((const char*)w1c_f + swz(s), (char*)wlds + s);
    }
  }

  const int4 g0 = *(const int4*)(idx + (nb0 + row0 + 0) * M_NBR + c * 4);
  const int4 g1 = *(const int4*)(idx + (nb0 + row0 + 1) * M_NBR + c * 4);
  const int4 g2 = *(const int4*)(idx + (nb0 + row0 + 2) * M_NBR + c * 4);
  const int4 g3 = *(const int4*)(idx + (nb0 + row0 + 3) * M_NBR + c * 4);

  __syncthreads();

  NL va = load_node(nbr, t1bp, t2bp, nb0 + row0 + 0, g0, r, c);
  NL vb = load_node(nbr, t1bp, t2bp, nb0 + row0 + 1, g1, r, c);
  FENCE();
  compute_node(va, wlds, hlds, row0 + 0, lane, r, c);

  va = load_node(nbr, t1bp, t2bp, nb0 + row0 + 2, g2, r, c);
  FENCE();
  compute_node(vb, wlds, hlds, row0 + 1, lane, r, c);

  vb = load_node(nbr, t1bp, t2bp, nb0 + row0 + 3, g3, r, c);
  FENCE();
  compute_node(va, wlds, hlds, row0 + 2, lane, r, c);
  compute_node(vb, wlds, hlds, row0 + 3, lane, r, c);

  __syncthreads();

  const int dtA = wid * 2, dtB = wid * 2 + 1;
  const bf16x8* w2 = (const bf16x8*)w2_f;
  bf16x8 bA[4], bB[4];
  #pragma unroll
  for (int kt = 0; kt < 4; ++kt) {
    bA[kt] = w2[(dtA * 4 + kt) * 64 + c * 16 + r];
    bB[kt] = w2[(dtB * 4 + kt) * 64 + c * 16 + r];
  }
  bf16x8 haf[4];
  #pragma unroll
  for (int kt = 0; kt < 4; ++kt)
    haf[kt] = *(const bf16x8*)(hlds + r * HPITCH + kt * 32 + c * 8);

  f32x4 accA = (f32x4){0,0,0,0}, accB = (f32x4){0,0,0,0};
  #pragma unroll
  for (int kt = 0; kt < 4; ++kt) {
    accA = __builtin_amdgcn_mfma_f32_16x16x32_bf16(haf[kt], bA[kt], accA, 0, 0, 0);
    accB = __builtin_amdgcn_mfma_f32_16x16x32_bf16(haf[kt], bB[kt], accB, 0, 0, 0);
  }

  const float b2A = 16.0f * b2[dtA * 16 + r];
  const float b2B = 16.0f * b2[dtB * 16 + r];
  #pragma unroll
  for (int j = 0; j < 4; ++j) {
    const int node = nb0 + c * 4 + j;
    const size_t oA = (size_t)node * 128 + dtA * 16 + r;
    const size_t oB = (size_t)node * 128 + dtB * 16 + r;
    out[oA] = x[oA] + accA[j] + b2A;
    out[oB] = x[oB] + accB[j] + b2B;
  }
}

// ---------------------------------------------------------------------------
extern "C" void kernel_launch(void* const* d_in, const int* in_sizes, int n_in,
                              void* d_out, int out_size, void* d_ws, size_t ws_size,
                              hipStream_t stream) {
  const float* x        = (const float*)d_in[0];
  const float* nbr_fea  = (const float*)d_in[1];
  const int*   nbr_idx  = (const int*)d_in[2];
  const float* ln_scale = (const float*)d_in[3];
  const float* ln_bias  = (const float*)d_in[4];
  const float* W1       = (const float*)d_in[5];
  const float* b1       = (const float*)d_in[6];
  const float* W2       = (const float*)d_in[7];
  const float* b2       = (const float*)d_in[8];
  float* out = (float*)d_out;

  char* ws = (char*)d_ws;
  __bf16* t1bp   = (__bf16*)(ws);                      // 12,800,000 B
  __bf16* t2bp   = (__bf16*)(ws + 12800000);           // 12,800,000 B
  __bf16* w1a_f  = (__bf16*)(ws + 25600000);           //     32,768 B
  __bf16* w1b_f  = (__bf16*)(ws + 25632768);           //     32,768 B
  __bf16* w1c_f  = (__bf16*)(ws + 25665536);           //     16,384 B
  __bf16* w2_f   = (__bf16*)(ws + 25681920);           //     32,768 B
  float*  scrA   = (float*)(ws + 25714688);            //  3,200,000 B
  float*  scrB   = (float*)(ws + 28914688);            //  3,200,000 B
  float*  scrC   = (float*)(ws + 32114688);            //  3,200,000 B

  // ---- instrumentation: phase ablations (outputs to scratch only) ----
  k_prep    <<<224, 256, 0, stream>>>(W1, W2, w1a_f, w1b_f, w1c_f, w2_f);
  kA_stream <<<N_NODES / 16, 256, 0, stream>>>(nbr_fea, w1c_f, scrA);
  kB_gather <<<N_NODES / 16, 256, 0, stream>>>(nbr_idx, t1bp, t2bp, scrB);
  kC_silu   <<<N_NODES / 16, 256, 0, stream>>>(scrC);

  // ---- real pipeline (R17, best-known) ----
  k_t12f  <<<(N_NODES / 16 + 3) / 4, 256, 0, stream>>>(x, ln_scale, ln_bias,
                                                       w1a_f, w1b_f, b1, t1bp, t2bp);
  k_edge2 <<<N_NODES / 16, 256, 0, stream>>>(nbr_fea, nbr_idx, t1bp, t2bp,
                                             w1c_f, w2_f, b2, x, out);
}

// Round 19
// 153.781 us; speedup vs baseline: 1.4401x; 1.4401x over previous
//
#include <hip/hip_runtime.h>
#include <math.h>

#define N_NODES 50000
#define M_NBR 16
#define D 128
#define E 64

typedef __attribute__((ext_vector_type(8))) __bf16 bf16x8;
typedef __attribute__((ext_vector_type(4))) float f32x4;

// async global->LDS (per-lane global src; wave-uniform LDS base + lane*16)
__device__ __forceinline__ void gload16(const void* g, void* l) {
  __builtin_amdgcn_global_load_lds(
      (const __attribute__((address_space(1))) void*)g,
      (__attribute__((address_space(3))) void*)l, 16, 0, 0);
}

// W1c LDS swizzle (involution; conflict-free b128 reads)
__device__ __forceinline__ int swz(int o) { return o ^ (((o >> 7) & 7) << 4); }

// Fragment-permuted weight storage (bf16):
//   flat = (((dt*NKT + kt)*4 + c)*16 + r)*8 + j
// holds W_natural[k = kt*32 + c*8 + j][d = dt*16 + r].

// ---------------------------------------------------------------------------
// K0: build fragment-permuted bf16 weights.  W2 k-REMAPPED (R15 version:
// matches permuted [n][r*8+dt] hsum layout consumed by k_out).
// ---------------------------------------------------------------------------
__global__ __launch_bounds__(256) void k_prep(const float* __restrict__ W1,
                                              const float* __restrict__ W2,
                                              __bf16* __restrict__ w1a_f,
                                              __bf16* __restrict__ w1b_f,
                                              __bf16* __restrict__ w1c_f,
                                              __bf16* __restrict__ w2_f) {
  const int t = blockIdx.x * 256 + threadIdx.x;
  if (t < 16384) {                       // W1a
    const int j = t & 7, r = (t >> 3) & 15, c = (t >> 7) & 3, q = t >> 9;
    const int kt = q & 3, dt = q >> 2;
    w1a_f[t] = (__bf16)W1[(kt * 32 + c * 8 + j) * 128 + dt * 16 + r];
  } else if (t < 32768) {                // W1b
    const int u = t - 16384;
    const int j = u & 7, r = (u >> 3) & 15, c = (u >> 7) & 3, q = u >> 9;
    const int kt = q & 3, dt = q >> 2;
    w1b_f[u] = (__bf16)W1[(128 + kt * 32 + c * 8 + j) * 128 + dt * 16 + r];
  } else if (t < 40960) {                // W1c (NKT=2)
    const int u = t - 32768;
    const int j = u & 7, r = (u >> 3) & 15, c = (u >> 7) & 3, q = u >> 9;
    const int kt = q & 1, dt = q >> 1;
    w1c_f[u] = (__bf16)W1[(256 + kt * 32 + c * 8 + j) * 128 + dt * 16 + r];
  } else if (t < 57344) {                // W2, permuted k (R15)
    const int u = t - 40960;
    const int j = u & 7, r = (u >> 3) & 15, c = (u >> 7) & 3, q = u >> 9;
    const int kt = q & 3, dt = q >> 2;
    const int i = kt * 32 + c * 8 + j;             // stored-k
    const int ak = (i & 7) * 16 + (i >> 3);        // natural k in hsum row
    w2_f[u] = (__bf16)W2[ak * 128 + dt * 16 + r];
  }
}

// ---------------------------------------------------------------------------
// K1: fused LayerNorm + dual GEMM via MFMA.  (unchanged, known-good)
// Outputs permuted [n][r*8+dt]: t1bp (b1 folded), t2bp.
// ---------------------------------------------------------------------------
__global__ __launch_bounds__(256) void k_t12f(const float* __restrict__ x,
                                              const float* __restrict__ sc,
                                              const float* __restrict__ bi,
                                              const __bf16* __restrict__ w1a_f,
                                              const __bf16* __restrict__ w1b_f,
                                              const float* __restrict__ b1,
                                              __bf16* __restrict__ t1bp,
                                              __bf16* __restrict__ t2bp) {
  const int wave = blockIdx.x * 4 + (threadIdx.x >> 6);
  if (wave >= N_NODES / 16) return;
  const int lane = threadIdx.x & 63;
  const int r = lane & 15, c = lane >> 4;
  const int node0 = wave * 16;

  const float* row = x + (size_t)(node0 + r) * 128 + c * 8;
  f32x4 va[8];
  #pragma unroll
  for (int kt = 0; kt < 4; ++kt) {
    va[2 * kt]     = *(const f32x4*)(row + kt * 32);
    va[2 * kt + 1] = *(const f32x4*)(row + kt * 32 + 4);
  }
  float s = 0.f;
  #pragma unroll
  for (int q = 0; q < 8; ++q) s += va[q][0] + va[q][1] + va[q][2] + va[q][3];
  s += __shfl_xor(s, 16, 64);
  s += __shfl_xor(s, 32, 64);
  const float mu = s * (1.0f / 128.0f);
  float qs = 0.f;
  #pragma unroll
  for (int q = 0; q < 8; ++q) {
    #pragma unroll
    for (int e = 0; e < 4; ++e) { const float dxx = va[q][e] - mu; qs += dxx * dxx; }
  }
  qs += __shfl_xor(qs, 16, 64);
  qs += __shfl_xor(qs, 32, 64);
  const float rs = rsqrtf(qs * (1.0f / 128.0f) + 1e-6f);

  bf16x8 af[4];
  #pragma unroll
  for (int kt = 0; kt < 4; ++kt) {
    const f32x4 s_lo = *(const f32x4*)(sc + kt * 32 + c * 8);
    const f32x4 s_hi = *(const f32x4*)(sc + kt * 32 + c * 8 + 4);
    const f32x4 b_lo = *(const f32x4*)(bi + kt * 32 + c * 8);
    const f32x4 b_hi = *(const f32x4*)(bi + kt * 32 + c * 8 + 4);
    #pragma unroll
    for (int e = 0; e < 4; ++e) {
      af[kt][e]     = (__bf16)(((va[2 * kt][e]     - mu) * rs) * s_lo[e] + b_lo[e]);
      af[kt][4 + e] = (__bf16)(((va[2 * kt + 1][e] - mu) * rs) * s_hi[e] + b_hi[e]);
    }
  }

  const bf16x8* wa = (const bf16x8*)w1a_f;
  const bf16x8* wb = (const bf16x8*)w1b_f;
  f32x4 acc1[8], acc2[8];
  #pragma unroll
  for (int dt = 0; dt < 8; ++dt) { acc1[dt] = (f32x4){0,0,0,0}; acc2[dt] = (f32x4){0,0,0,0}; }
  #pragma unroll
  for (int dt = 0; dt < 8; ++dt) {
    #pragma unroll
    for (int kt = 0; kt < 4; ++kt) {
      const bf16x8 bfa = wa[(dt * 4 + kt) * 64 + c * 16 + r];
      acc1[dt] = __builtin_amdgcn_mfma_f32_16x16x32_bf16(af[kt], bfa, acc1[dt], 0, 0, 0);
      const bf16x8 bfb = wb[(dt * 4 + kt) * 64 + c * 16 + r];
      acc2[dt] = __builtin_amdgcn_mfma_f32_16x16x32_bf16(af[kt], bfb, acc2[dt], 0, 0, 0);
    }
  }

  float b1v[8];
  #pragma unroll
  for (int dt = 0; dt < 8; ++dt) b1v[dt] = b1[dt * 16 + r];
  #pragma unroll
  for (int j = 0; j < 4; ++j) {
    const int node = node0 + c * 4 + j;
    bf16x8 t1v, t2v;
    #pragma unroll
    for (int dt = 0; dt < 8; ++dt) {
      t1v[dt] = (__bf16)(acc1[dt][j] + b1v[dt]);
      t2v[dt] = (__bf16)acc2[dt][j];
    }
    *(bf16x8*)(t1bp + (size_t)node * 128 + r * 8) = t1v;
    *(bf16x8*)(t2bp + (size_t)node * 128 + r * 8) = t2v;
  }
}

// ---------------------------------------------------------------------------
// K2, R19: WAVE-SPECIALIZED edge kernel.  Block = 192 thr = 3 waves, 8 nodes.
//   wave 2 (gather): relays t1 rows (2 insts) + all 8 nodes' t2 rows
//     (32 gload16, per-lane random src, XOR-swizzled source -> 2-way LDS reads)
//   waves 0-1 (compute): stage W1c (8 chunks each) + pre-issue their pure-
//     coalesced nbr streams to VGPRs.
//   ONE __syncthreads: every wave drains only its OWN homogeneous queue;
//   stream, gather, W1c latencies land in one parallel window.  After it:
//   pure LDS/MFMA/VALU + hsum store.  3 blocks/CU stagger the windows.
// ---------------------------------------------------------------------------
struct SA { f32x4 a0, a1, a2, a3; };

__device__ __forceinline__ SA load_stream(const float* __restrict__ nbr,
                                          int n, int r, int c) {
  SA v;
  const float* arow = nbr + (size_t)n * (M_NBR * E) + r * E + c * 8;
  v.a0 = *(const f32x4*)(arow);
  v.a1 = *(const f32x4*)(arow + 4);
  v.a2 = *(const f32x4*)(arow + 32);
  v.a3 = *(const f32x4*)(arow + 36);
  return v;
}

__device__ __forceinline__ void compute_node(const SA& v, const __bf16* wlds,
                                             const __bf16* tgl, const __bf16* t1l,
                                             int slot, int n, int lane, int r, int c,
                                             __bf16* __restrict__ hsum_b) {
  bf16x8 af0, af1;
  #pragma unroll
  for (int e = 0; e < 4; ++e) {
    af0[e] = (__bf16)v.a0[e]; af0[4 + e] = (__bf16)v.a1[e];
    af1[e] = (__bf16)v.a2[e]; af1[4 + e] = (__bf16)v.a3[e];
  }
  f32x4 acc[8];
  #pragma unroll
  for (int dt = 0; dt < 8; ++dt) acc[dt] = (f32x4){0, 0, 0, 0};
  #pragma unroll
  for (int dt = 0; dt < 8; ++dt) {
    const int o0 = ((dt * 2 + 0) * 64 + c * 16 + r) * 16;
    const int o1 = ((dt * 2 + 1) * 64 + c * 16 + r) * 16;
    const bf16x8 b0 = *(const bf16x8*)((const char*)wlds + swz(o0));
    const bf16x8 b1 = *(const bf16x8*)((const char*)wlds + swz(o1));
    acc[dt] = __builtin_amdgcn_mfma_f32_16x16x32_bf16(af0, b0, acc[dt], 0, 0, 0);
    acc[dt] = __builtin_amdgcn_mfma_f32_16x16x32_bf16(af1, b1, acc[dt], 0, 0, 0);
  }
  // tg rows from relay LDS (swizzled: row rho holds cols r^(rho&7))
  const bf16x8 tg0 = *(const bf16x8*)((const char*)tgl + slot * 4096 + (c * 4 + 0) * 256 + ((r ^ ((c * 4 + 0) & 7)) * 16));
  const bf16x8 tg1 = *(const bf16x8*)((const char*)tgl + slot * 4096 + (c * 4 + 1) * 256 + ((r ^ ((c * 4 + 1) & 7)) * 16));
  const bf16x8 tg2 = *(const bf16x8*)((const char*)tgl + slot * 4096 + (c * 4 + 2) * 256 + ((r ^ ((c * 4 + 2) & 7)) * 16));
  const bf16x8 tg3 = *(const bf16x8*)((const char*)tgl + slot * 4096 + (c * 4 + 3) * 256 + ((r ^ ((c * 4 + 3) & 7)) * 16));
  const bf16x8 t1v = *(const bf16x8*)((const char*)t1l + slot * 256 + r * 16);

  float ssum[8];
  #pragma unroll
  for (int dt = 0; dt < 8; ++dt) {
    const float tb = (float)t1v[dt];
    float s = 0.f;
    { const float h = acc[dt][0] + tb + (float)tg0[dt]; s += __fdividef(h, 1.0f + __expf(-h)); }
    { const float h = acc[dt][1] + tb + (float)tg1[dt]; s += __fdividef(h, 1.0f + __expf(-h)); }
    { const float h = acc[dt][2] + tb + (float)tg2[dt]; s += __fdividef(h, 1.0f + __expf(-h)); }
    { const float h = acc[dt][3] + tb + (float)tg3[dt]; s += __fdividef(h, 1.0f + __expf(-h)); }
    s += __shfl_xor(s, 16, 64);
    s += __shfl_xor(s, 32, 64);
    ssum[dt] = s;
  }
  if (lane < 16) {
    bf16x8 hs;
    #pragma unroll
    for (int dt = 0; dt < 8; ++dt) hs[dt] = (__bf16)ssum[dt];
    *(bf16x8*)(hsum_b + (size_t)n * 128 + r * 8) = hs;
  }
}

__global__ __launch_bounds__(192, 2) void k_edge3(const float* __restrict__ nbr,
                                                  const int* __restrict__ idx,
                                                  const __bf16* __restrict__ t1bp,
                                                  const __bf16* __restrict__ t2bp,
                                                  const __bf16* __restrict__ w1c_f,
                                                  __bf16* __restrict__ hsum_b) {
  __shared__ __bf16 wlds[8192];        // 16 KB W1c (swizzled)
  __shared__ __bf16 tgl[8 * 2048];     // 32 KB t2-row relay (8 slots x 4KB)
  __shared__ __bf16 t1l[8 * 128];      // 2 KB t1 relay
  const int lane = threadIdx.x & 63;
  const int wid  = threadIdx.x >> 6;   // 0,1 = compute; 2 = gather
  const int r = lane & 15, c = lane >> 4;
  const int nb0 = blockIdx.x * 8;

  SA s0, s1, s2, s3;
  if (wid == 2) {
    // ---- gather wave: t1 relay (2 insts; dest linear = [nu][r] layout)
    {
      const int v0 = lane >> 4;
      gload16((const char*)t1bp + ((size_t)(nb0 + v0) * 128 + r * 8) * 2,
              (char*)t1l);
      const int v1 = 4 + (lane >> 4);
      gload16((const char*)t1bp + ((size_t)(nb0 + v1) * 128 + r * 8) * 2,
              (char*)t1l + 1024);
    }
    // ---- t2-row relay: 8 nodes x 4 chunks; chunk = 4 rows (64 lanes x 16B).
    // Source col pre-swizzled: LDS[nu, rho, r] = rowdata[r ^ (rho&7)].
    #pragma unroll
    for (int v = 0; v < 8; ++v) {
      #pragma unroll
      for (int k = 0; k < 4; ++k) {
        const int rho = k * 4 + (lane >> 4);
        const int g = idx[(nb0 + v) * M_NBR + rho];
        const int rs = (lane & 15) ^ (rho & 7);
        gload16((const char*)t2bp + ((size_t)g * 128 + rs * 8) * 2,
                (char*)tgl + v * 4096 + k * 1024);
      }
    }
  } else {
    // ---- compute waves: stage W1c (8 x 1KB chunks each; pre-swizzled src)
    #pragma unroll
    for (int q = 0; q < 8; ++q) {
      const int chunk = wid * 8 + q;
      const int s = chunk * 1024 + lane * 16;
      gload16((const char*)w1c_f + swz(s), (char*)wlds + chunk * 1024);
    }
    // ---- pre-issue this wave's 4 pure-coalesced node streams
    s0 = load_stream(nbr, nb0 + wid * 4 + 0, r, c);
    s1 = load_stream(nbr, nb0 + wid * 4 + 1, r, c);
    s2 = load_stream(nbr, nb0 + wid * 4 + 2, r, c);
    s3 = load_stream(nbr, nb0 + wid * 4 + 3, r, c);
  }

  __syncthreads();   // ONE latency window: each wave drains its own queue
  if (wid == 2) return;

  const int slot0 = wid * 4;
  compute_node(s0, wlds, tgl, t1l, slot0 + 0, nb0 + slot0 + 0, lane, r, c, hsum_b);
  compute_node(s1, wlds, tgl, t1l, slot0 + 1, nb0 + slot0 + 1, lane, r, c, hsum_b);
  compute_node(s2, wlds, tgl, t1l, slot0 + 2, nb0 + slot0 + 2, lane, r, c, hsum_b);
  compute_node(s3, wlds, tgl, t1l, slot0 + 3, nb0 + slot0 + 3, lane, r, c, hsum_b);
}

// ---------------------------------------------------------------------------
// K3: out = x + hsum@W2 + 16*b2 via MFMA.  (R15 version, known-good:
// bf16 permuted hsum input, k-remapped w2_f.)
// ---------------------------------------------------------------------------
__global__ __launch_bounds__(256) void k_out(const __bf16* __restrict__ hsum_b,
                                             const __bf16* __restrict__ w2_f,
                                             const float* __restrict__ b2,
                                             const float* __restrict__ x,
                                             float* __restrict__ out) {
  const int wave = blockIdx.x * 4 + (threadIdx.x >> 6);
  if (wave >= N_NODES / 16) return;
  const int lane = threadIdx.x & 63;
  const int r = lane & 15, c = lane >> 4;
  const int node0 = wave * 16;

  const __bf16* row = hsum_b + (size_t)(node0 + r) * 128 + c * 8;
  bf16x8 af[4];
  #pragma unroll
  for (int kt = 0; kt < 4; ++kt) af[kt] = *(const bf16x8*)(row + kt * 32);

  const bf16x8* w2 = (const bf16x8*)w2_f;
  f32x4 acc[8];
  #pragma unroll
  for (int dt = 0; dt < 8; ++dt) acc[dt] = (f32x4){0,0,0,0};
  #pragma unroll
  for (int dt = 0; dt < 8; ++dt) {
    #pragma unroll
    for (int kt = 0; kt < 4; ++kt) {
      const bf16x8 bf = w2[(dt * 4 + kt) * 64 + c * 16 + r];
      acc[dt] = __builtin_amdgcn_mfma_f32_16x16x32_bf16(af[kt], bf, acc[dt], 0, 0, 0);
    }
  }

  float b2v[8];
  #pragma unroll
  for (int dt = 0; dt < 8; ++dt) b2v[dt] = 16.0f * b2[dt * 16 + r];
  #pragma unroll
  for (int j = 0; j < 4; ++j) {
    const int node = node0 + c * 4 + j;
    #pragma unroll
    for (int dt = 0; dt < 8; ++dt) {
      const size_t o = (size_t)node * 128 + dt * 16 + r;
      out[o] = x[o] + acc[dt][j] + b2v[dt];
    }
  }
}

// ---------------------------------------------------------------------------
extern "C" void kernel_launch(void* const* d_in, const int* in_sizes, int n_in,
                              void* d_out, int out_size, void* d_ws, size_t ws_size,
                              hipStream_t stream) {
  const float* x        = (const float*)d_in[0];
  const float* nbr_fea  = (const float*)d_in[1];
  const int*   nbr_idx  = (const int*)d_in[2];
  const float* ln_scale = (const float*)d_in[3];
  const float* ln_bias  = (const float*)d_in[4];
  const float* W1       = (const float*)d_in[5];
  const float* b1       = (const float*)d_in[6];
  const float* W2       = (const float*)d_in[7];
  const float* b2       = (const float*)d_in[8];
  float* out = (float*)d_out;

  char* ws = (char*)d_ws;
  __bf16* t1bp   = (__bf16*)(ws);                      // 12,800,000 B
  __bf16* t2bp   = (__bf16*)(ws + 12800000);           // 12,800,000 B
  __bf16* hsum_b = (__bf16*)(ws + 25600000);           // 12,800,000 B
  __bf16* w1a_f  = (__bf16*)(ws + 38400000);           //     32,768 B
  __bf16* w1b_f  = (__bf16*)(ws + 38432768);           //     32,768 B
  __bf16* w1c_f  = (__bf16*)(ws + 38465536);           //     16,384 B
  __bf16* w2_f   = (__bf16*)(ws + 38481920);           //     32,768 B

  k_prep  <<<224, 256, 0, stream>>>(W1, W2, w1a_f, w1b_f, w1c_f, w2_f);
  k_t12f  <<<(N_NODES / 16 + 3) / 4, 256, 0, stream>>>(x, ln_scale, ln_bias,
                                                       w1a_f, w1b_f, b1, t1bp, t2bp);
  k_edge3 <<<N_NODES / 8, 192, 0, stream>>>(nbr_fea, nbr_idx, t1bp, t2bp,
                                            w1c_f, hsum_b);
  k_out   <<<(N_NODES / 16 + 3) / 4, 256, 0, stream>>>(hsum_b, w2_f, b2, x, out);
}

// Round 20
// 114.629 us; speedup vs baseline: 1.9319x; 1.3416x over previous
//
#include <hip/hip_runtime.h>
#include <math.h>

#define N_NODES 50000
#define M_NBR 16
#define D 128
#define E 64

typedef __attribute__((ext_vector_type(8))) __bf16 bf16x8;
typedef __attribute__((ext_vector_type(4))) float f32x4;

// async global->LDS (HW: per-lane global src; wave-uniform LDS base + lane*16)
__device__ __forceinline__ void gload16(const void* g, void* l) {
  __builtin_amdgcn_global_load_lds(
      (const __attribute__((address_space(1))) void*)g,
      (__attribute__((address_space(3))) void*)l, 16, 0, 0);
}

// Memory-clobber fence: memory ops cannot legally cross.
#define FENCE() asm volatile("" ::: "memory")

// W1c LDS swizzle: stored[s] = orig[s ^ (((s>>7)&7)<<4)]  (involution)
__device__ __forceinline__ int swz(int o) { return o ^ (((o >> 7) & 7) << 4); }

// Fragment-permuted weight storage (bf16):
//   flat = (((dt*NKT + kt)*4 + c)*16 + r)*8 + j
// holds W_natural[k = kt*32 + c*8 + j][d = dt*16 + r].

// ---------------------------------------------------------------------------
// K0: build fragment-permuted bf16 weights.  (W2 natural-k for fused kernel)
// ---------------------------------------------------------------------------
__global__ __launch_bounds__(256) void k_prep(const float* __restrict__ W1,
                                              const float* __restrict__ W2,
                                              __bf16* __restrict__ w1a_f,
                                              __bf16* __restrict__ w1b_f,
                                              __bf16* __restrict__ w1c_f,
                                              __bf16* __restrict__ w2_f) {
  const int t = blockIdx.x * 256 + threadIdx.x;
  if (t < 16384) {                       // W1a
    const int j = t & 7, r = (t >> 3) & 15, c = (t >> 7) & 3, q = t >> 9;
    const int kt = q & 3, dt = q >> 2;
    w1a_f[t] = (__bf16)W1[(kt * 32 + c * 8 + j) * 128 + dt * 16 + r];
  } else if (t < 32768) {                // W1b
    const int u = t - 16384;
    const int j = u & 7, r = (u >> 3) & 15, c = (u >> 7) & 3, q = u >> 9;
    const int kt = q & 3, dt = q >> 2;
    w1b_f[u] = (__bf16)W1[(128 + kt * 32 + c * 8 + j) * 128 + dt * 16 + r];
  } else if (t < 40960) {                // W1c (NKT=2)
    const int u = t - 32768;
    const int j = u & 7, r = (u >> 3) & 15, c = (u >> 7) & 3, q = u >> 9;
    const int kt = q & 1, dt = q >> 1;
    w1c_f[u] = (__bf16)W1[(256 + kt * 32 + c * 8 + j) * 128 + dt * 16 + r];
  } else if (t < 57344) {                // W2, NATURAL k
    const int u = t - 40960;
    const int j = u & 7, r = (u >> 3) & 15, c = (u >> 7) & 3, q = u >> 9;
    const int kt = q & 3, dt = q >> 2;
    w2_f[u] = (__bf16)W2[(kt * 32 + c * 8 + j) * 128 + dt * 16 + r];
  }
}

// ---------------------------------------------------------------------------
// K1: fused LayerNorm + dual GEMM via MFMA.  (known-good)
// ---------------------------------------------------------------------------
__global__ __launch_bounds__(256) void k_t12f(const float* __restrict__ x,
                                              const float* __restrict__ sc,
                                              const float* __restrict__ bi,
                                              const __bf16* __restrict__ w1a_f,
                                              const __bf16* __restrict__ w1b_f,
                                              const float* __restrict__ b1,
                                              __bf16* __restrict__ t1bp,
                                              __bf16* __restrict__ t2bp) {
  const int wave = blockIdx.x * 4 + (threadIdx.x >> 6);
  if (wave >= N_NODES / 16) return;
  const int lane = threadIdx.x & 63;
  const int r = lane & 15, c = lane >> 4;
  const int node0 = wave * 16;

  const float* row = x + (size_t)(node0 + r) * 128 + c * 8;
  f32x4 va[8];
  #pragma unroll
  for (int kt = 0; kt < 4; ++kt) {
    va[2 * kt]     = *(const f32x4*)(row + kt * 32);
    va[2 * kt + 1] = *(const f32x4*)(row + kt * 32 + 4);
  }
  float s = 0.f;
  #pragma unroll
  for (int q = 0; q < 8; ++q) s += va[q][0] + va[q][1] + va[q][2] + va[q][3];
  s += __shfl_xor(s, 16, 64);
  s += __shfl_xor(s, 32, 64);
  const float mu = s * (1.0f / 128.0f);
  float qs = 0.f;
  #pragma unroll
  for (int q = 0; q < 8; ++q) {
    #pragma unroll
    for (int e = 0; e < 4; ++e) { const float dxx = va[q][e] - mu; qs += dxx * dxx; }
  }
  qs += __shfl_xor(qs, 16, 64);
  qs += __shfl_xor(qs, 32, 64);
  const float rs = rsqrtf(qs * (1.0f / 128.0f) + 1e-6f);

  bf16x8 af[4];
  #pragma unroll
  for (int kt = 0; kt < 4; ++kt) {
    const f32x4 s_lo = *(const f32x4*)(sc + kt * 32 + c * 8);
    const f32x4 s_hi = *(const f32x4*)(sc + kt * 32 + c * 8 + 4);
    const f32x4 b_lo = *(const f32x4*)(bi + kt * 32 + c * 8);
    const f32x4 b_hi = *(const f32x4*)(bi + kt * 32 + c * 8 + 4);
    #pragma unroll
    for (int e = 0; e < 4; ++e) {
      af[kt][e]     = (__bf16)(((va[2 * kt][e]     - mu) * rs) * s_lo[e] + b_lo[e]);
      af[kt][4 + e] = (__bf16)(((va[2 * kt + 1][e] - mu) * rs) * s_hi[e] + b_hi[e]);
    }
  }

  const bf16x8* wa = (const bf16x8*)w1a_f;
  const bf16x8* wb = (const bf16x8*)w1b_f;
  f32x4 acc1[8], acc2[8];
  #pragma unroll
  for (int dt = 0; dt < 8; ++dt) { acc1[dt] = (f32x4){0,0,0,0}; acc2[dt] = (f32x4){0,0,0,0}; }
  #pragma unroll
  for (int dt = 0; dt < 8; ++dt) {
    #pragma unroll
    for (int kt = 0; kt < 4; ++kt) {
      const bf16x8 bfa = wa[(dt * 4 + kt) * 64 + c * 16 + r];
      acc1[dt] = __builtin_amdgcn_mfma_f32_16x16x32_bf16(af[kt], bfa, acc1[dt], 0, 0, 0);
      const bf16x8 bfb = wb[(dt * 4 + kt) * 64 + c * 16 + r];
      acc2[dt] = __builtin_amdgcn_mfma_f32_16x16x32_bf16(af[kt], bfb, acc2[dt], 0, 0, 0);
    }
  }

  float b1v[8];
  #pragma unroll
  for (int dt = 0; dt < 8; ++dt) b1v[dt] = b1[dt * 16 + r];
  #pragma unroll
  for (int j = 0; j < 4; ++j) {
    const int node = node0 + c * 4 + j;
    bf16x8 t1v, t2v;
    #pragma unroll
    for (int dt = 0; dt < 8; ++dt) {
      t1v[dt] = (__bf16)(acc1[dt][j] + b1v[dt]);
      t2v[dt] = (__bf16)acc2[dt][j];
    }
    *(bf16x8*)(t1bp + (size_t)node * 128 + r * 8) = t1v;
    *(bf16x8*)(t2bp + (size_t)node * 128 + r * 8) = t2v;
  }
}

// ---------------------------------------------------------------------------
// K2 (fused, R17 best-known): W1c in LDS (one barrier), 2-deep VGPR-staged
// phase-2 with memory-clobber fences, hsum -> LDS tile, in-block W2 GEMM +
// residual + store.
// ---------------------------------------------------------------------------
#define HPITCH 136

struct NL {
  f32x4 a0, a1, a2, a3;          // nbr A-row pieces (fp32)
  bf16x8 t1v;                    // t1 row (b1 folded)
  bf16x8 tg0, tg1, tg2, tg3;     // gathered t2 rows
};

__device__ __forceinline__ NL load_node(const float* __restrict__ nbr,
                                        const __bf16* __restrict__ t1bp,
                                        const __bf16* __restrict__ t2bp,
                                        int n, int4 g, int r, int c) {
  NL v;
  const float* arow = nbr + (size_t)n * (M_NBR * E) + r * E + c * 8;
  v.a0 = *(const f32x4*)(arow);
  v.a1 = *(const f32x4*)(arow + 4);
  v.a2 = *(const f32x4*)(arow + 32);
  v.a3 = *(const f32x4*)(arow + 36);
  v.t1v = *(const bf16x8*)(t1bp + (size_t)n * 128 + r * 8);
  v.tg0 = *(const bf16x8*)(t2bp + (size_t)g.x * 128 + r * 8);
  v.tg1 = *(const bf16x8*)(t2bp + (size_t)g.y * 128 + r * 8);
  v.tg2 = *(const bf16x8*)(t2bp + (size_t)g.z * 128 + r * 8);
  v.tg3 = *(const bf16x8*)(t2bp + (size_t)g.w * 128 + r * 8);
  return v;
}

__device__ __forceinline__ void compute_node(const NL& v, const __bf16* wlds,
                                             __bf16* hlds, int row,
                                             int lane, int r, int c) {
  bf16x8 af0, af1;
  #pragma unroll
  for (int e = 0; e < 4; ++e) {
    af0[e] = (__bf16)v.a0[e]; af0[4 + e] = (__bf16)v.a1[e];
    af1[e] = (__bf16)v.a2[e]; af1[4 + e] = (__bf16)v.a3[e];
  }
  f32x4 acc[8];
  #pragma unroll
  for (int dt = 0; dt < 8; ++dt) acc[dt] = (f32x4){0, 0, 0, 0};
  #pragma unroll
  for (int dt = 0; dt < 8; ++dt) {
    const int o0 = ((dt * 2 + 0) * 64 + c * 16 + r) * 16;
    const int o1 = ((dt * 2 + 1) * 64 + c * 16 + r) * 16;
    const bf16x8 b0 = *(const bf16x8*)((const char*)wlds + swz(o0));
    const bf16x8 b1 = *(const bf16x8*)((const char*)wlds + swz(o1));
    acc[dt] = __builtin_amdgcn_mfma_f32_16x16x32_bf16(af0, b0, acc[dt], 0, 0, 0);
    acc[dt] = __builtin_amdgcn_mfma_f32_16x16x32_bf16(af1, b1, acc[dt], 0, 0, 0);
  }
  #pragma unroll
  for (int dt = 0; dt < 8; ++dt) {
    const float tb = (float)v.t1v[dt];
    float s = 0.f;
    { const float h = acc[dt][0] + tb + (float)v.tg0[dt]; s += __fdividef(h, 1.0f + __expf(-h)); }
    { const float h = acc[dt][1] + tb + (float)v.tg1[dt]; s += __fdividef(h, 1.0f + __expf(-h)); }
    { const float h = acc[dt][2] + tb + (float)v.tg2[dt]; s += __fdividef(h, 1.0f + __expf(-h)); }
    { const float h = acc[dt][3] + tb + (float)v.tg3[dt]; s += __fdividef(h, 1.0f + __expf(-h)); }
    s += __shfl_xor(s, 16, 64);
    s += __shfl_xor(s, 32, 64);
    if (lane < 16) hlds[row * HPITCH + dt * 16 + lane] = (__bf16)s;
  }
}

__global__ __launch_bounds__(256, 3) void k_edge2(const float* __restrict__ nbr,
                                                  const int* __restrict__ idx,
                                                  const __bf16* __restrict__ t1bp,
                                                  const __bf16* __restrict__ t2bp,
                                                  const __bf16* __restrict__ w1c_f,
                                                  const __bf16* __restrict__ w2_f,
                                                  const float* __restrict__ b2,
                                                  const float* __restrict__ x,
                                                  float* __restrict__ out) {
  __shared__ __bf16 wlds[8192];            // 16 KB W1c, swizzled
  __shared__ __bf16 hlds[16 * HPITCH];     // 4.25 KB hsum tile, natural d
  const int lane = threadIdx.x & 63;
  const int wid  = threadIdx.x >> 6;
  const int r = lane & 15, c = lane >> 4;
  const int nb0 = blockIdx.x * 16;
  const int row0 = wid * 4;

  {
    const int s0 = wid * 1024 + lane * 16;
    #pragma unroll
    for (int q = 0; q < 4; ++q) {
      const int s = s0 + q * 4096;
      gload16((const char*)w1c_f + swz(s), (char*)wlds + s);
    }
  }

  const int4 g0 = *(const int4*)(idx + (nb0 + row0 + 0) * M_NBR + c * 4);
  const int4 g1 = *(const int4*)(idx + (nb0 + row0 + 1) * M_NBR + c * 4);
  const int4 g2 = *(const int4*)(idx + (nb0 + row0 + 2) * M_NBR + c * 4);
  const int4 g3 = *(const int4*)(idx + (nb0 + row0 + 3) * M_NBR + c * 4);

  __syncthreads();                          // W1c resident (one-time drain)

  NL va = load_node(nbr, t1bp, t2bp, nb0 + row0 + 0, g0, r, c);
  NL vb = load_node(nbr, t1bp, t2bp, nb0 + row0 + 1, g1, r, c);
  FENCE();
  compute_node(va, wlds, hlds, row0 + 0, lane, r, c);

  va = load_node(nbr, t1bp, t2bp, nb0 + row0 + 2, g2, r, c);
  FENCE();
  compute_node(vb, wlds, hlds, row0 + 1, lane, r, c);

  vb = load_node(nbr, t1bp, t2bp, nb0 + row0 + 3, g3, r, c);
  FENCE();
  compute_node(va, wlds, hlds, row0 + 2, lane, r, c);
  compute_node(vb, wlds, hlds, row0 + 3, lane, r, c);

  __syncthreads();                          // hsum tile resident

  const int dtA = wid * 2, dtB = wid * 2 + 1;
  const bf16x8* w2 = (const bf16x8*)w2_f;
  bf16x8 bA[4], bB[4];
  #pragma unroll
  for (int kt = 0; kt < 4; ++kt) {
    bA[kt] = w2[(dtA * 4 + kt) * 64 + c * 16 + r];
    bB[kt] = w2[(dtB * 4 + kt) * 64 + c * 16 + r];
  }
  bf16x8 haf[4];
  #pragma unroll
  for (int kt = 0; kt < 4; ++kt)
    haf[kt] = *(const bf16x8*)(hlds + r * HPITCH + kt * 32 + c * 8);

  f32x4 accA = (f32x4){0,0,0,0}, accB = (f32x4){0,0,0,0};
  #pragma unroll
  for (int kt = 0; kt < 4; ++kt) {
    accA = __builtin_amdgcn_mfma_f32_16x16x32_bf16(haf[kt], bA[kt], accA, 0, 0, 0);
    accB = __builtin_amdgcn_mfma_f32_16x16x32_bf16(haf[kt], bB[kt], accB, 0, 0, 0);
  }

  const float b2A = 16.0f * b2[dtA * 16 + r];
  const float b2B = 16.0f * b2[dtB * 16 + r];
  #pragma unroll
  for (int j = 0; j < 4; ++j) {
    const int node = nb0 + c * 4 + j;
    const size_t oA = (size_t)node * 128 + dtA * 16 + r;
    const size_t oB = (size_t)node * 128 + dtB * 16 + r;
    out[oA] = x[oA] + accA[j] + b2A;
    out[oB] = x[oB] + accB[j] + b2B;
  }
}

// ---------------------------------------------------------------------------
extern "C" void kernel_launch(void* const* d_in, const int* in_sizes, int n_in,
                              void* d_out, int out_size, void* d_ws, size_t ws_size,
                              hipStream_t stream) {
  const float* x        = (const float*)d_in[0];
  const float* nbr_fea  = (const float*)d_in[1];
  const int*   nbr_idx  = (const int*)d_in[2];
  const float* ln_scale = (const float*)d_in[3];
  const float* ln_bias  = (const float*)d_in[4];
  const float* W1       = (const float*)d_in[5];
  const float* b1       = (const float*)d_in[6];
  const float* W2       = (const float*)d_in[7];
  const float* b2       = (const float*)d_in[8];
  float* out = (float*)d_out;

  char* ws = (char*)d_ws;
  __bf16* t1bp   = (__bf16*)(ws);                      // 12,800,000 B
  __bf16* t2bp   = (__bf16*)(ws + 12800000);           // 12,800,000 B
  __bf16* w1a_f  = (__bf16*)(ws + 25600000);           //     32,768 B
  __bf16* w1b_f  = (__bf16*)(ws + 25632768);           //     32,768 B
  __bf16* w1c_f  = (__bf16*)(ws + 25665536);           //     16,384 B
  __bf16* w2_f   = (__bf16*)(ws + 25681920);           //     32,768 B

  k_prep  <<<224, 256, 0, stream>>>(W1, W2, w1a_f, w1b_f, w1c_f, w2_f);
  k_t12f  <<<(N_NODES / 16 + 3) / 4, 256, 0, stream>>>(x, ln_scale, ln_bias,
                                                       w1a_f, w1b_f, b1, t1bp, t2bp);
  k_edge2 <<<N_NODES / 16, 256, 0, stream>>>(nbr_fea, nbr_idx, t1bp, t2bp,
                                             w1c_f, w2_f, b2, x, out);
}